// Round 2
// baseline (191.261 us; speedup 1.0000x reference)
//
#include <hip/hip_runtime.h>

// NNConv / MPNN layer, fully fused — v2 "persistent W2" restructure (+LDS-size opt-in):
//   h  = relu(ef @ W1 + b1)            [E,128]   (bf16 MFMA, K=16)
//   We = h @ W2 + b2                   [E,32,32] (bf16 MFMA, K=128, acc in VGPR/AGPR, never stored)
//   msg= einsum('ei,eio->eo', nf[src], We)       (fp32 VALU on acc tiles)
//   out= segment_sum(msg, dst) + bias            (fp32 global atomics, out pre-init to bias)
//
// Structure: 256 blocks (1/CU) x 512 thr (8 waves). Output dim o split in 2 halves;
// per half, 128 KB of bf16 W2 (packed col c = i*16 + (o&15)) is staged ONCE into LDS
// via global_load_lds (source pre-swizzled to the exact LDS image by setup_kernel)
// and stays resident while the block grid-strides its 12-13 edge tiles.
// K-loop is barrier-free (W2s/Hs read-only), fully unrolled, with next-tile register
// prefetch (esrc -> nf gather, ef frag) folded in. 5 barriers per tile-pass.
// All LDS layouts stride-1 conflict-free:
//   W2s [ks8][ctile16][lh2][c32]x16B  (B-frag: 32 lanes read 512 contiguous bytes)
//   Hs  [G16][e^(G&7) 64]x16B        (A-frag reads and phase-1 writes both spread)
//   Xs  [e64][i32] f32               (writes stride-1, reads broadcast)
//   pbuf[4][e64][o16] f32 alias Hs   (writes 4-way = 1.58x, ~150cyc/tile, acceptable)

#define E_TOTAL   200000
#define N_NODES   50000
#define TILES     3125          // E_TOTAL / 64
#define OUT_BLKS  6250          // N_NODES*32 / 256
#define W2K_BLKS  512           // 131072 / 256
#define NBLK      256
#define NTL_BIG   53            // TILES % NBLK: blocks 0..52 own 13 tiles, rest 12
#define LDS_BYTES 159744        // 128K W2s + 4K W1Ts + 16K Hs + 8K Xs

typedef short short8  __attribute__((ext_vector_type(8)));
typedef float f32x16  __attribute__((ext_vector_type(16)));

__device__ __forceinline__ short f2bf(float f) {
    // round-to-nearest-even fp32 -> bf16 (inputs finite)
    union { float f; unsigned u; } cv; cv.f = f;
    unsigned r = cv.u + 0x7fffu + ((cv.u >> 16) & 1u);
    return (short)(r >> 16);
}

__device__ __forceinline__ void gll16(const short* gsrc, short* ldst) {
    // async global->LDS, 16B/lane; LDS dest = wave-uniform base + lane*16
    __builtin_amdgcn_global_load_lds(
        (const __attribute__((address_space(1))) unsigned int*)gsrc,
        (__attribute__((address_space(3))) unsigned int*)ldst, 16, 0, 0);
}

// ---------------- setup: out = bias; W2 f32 -> bf16 packed+pre-swizzled LDS image ----------------
// dest element (k, ci): i=ci>>5, o=ci&31, p=o>>4, c = i*16 + (o&15), ks=k>>4, kl=k&15
// idx = p*65536 + ks*8192 + (c>>5)*512 + (kl>>3)*256 + (c&31)*8 + (kl&7)
__global__ __launch_bounds__(256) void setup_kernel(const float* __restrict__ W2,
                                                    const float* __restrict__ bias,
                                                    float* __restrict__ out,
                                                    short* __restrict__ W2p) {
    int bid = blockIdx.x, tid = threadIdx.x;
    if (bid < OUT_BLKS) {
        int i = bid * 256 + tid;
        out[i] = bias[i & 31];
    } else {
        int g = (bid - OUT_BLKS) * 256 + tid;     // 0..131071, coalesced read of W2
        int k = g >> 10, ci = g & 1023;
        int i = ci >> 5, o = ci & 31;
        int p = o >> 4, o15 = o & 15;
        int c = i * 16 + o15;
        int ks = k >> 4, kl = k & 15;
        int idx = p * 65536 + ks * 8192 + (c >> 5) * 512 + (kl >> 3) * 256 + (c & 31) * 8 + (kl & 7);
        W2p[idx] = f2bf(W2[g]);
    }
}

// ---------------- main fused kernel ----------------
__global__ __launch_bounds__(512, 2) void mpnn_kernel(const float* __restrict__ nf,
                                                      const float* __restrict__ ef,
                                                      const int*   __restrict__ esrc,
                                                      const int*   __restrict__ edst,
                                                      const float* __restrict__ W1,
                                                      const float* __restrict__ b1,
                                                      const float* __restrict__ b2,
                                                      const short* __restrict__ W2p,
                                                      float* __restrict__ out) {
    extern __shared__ __align__(16) unsigned char smem[];
    short* W2s  = (short*)(smem);              // 131072 B: one o-half of W2, persistent per pass
    short* W1Ts = (short*)(smem + 131072);     //   4096 B: [128 c][16 k] bf16 swizzled, persistent
    short* Hs   = (short*)(smem + 135168);     //  16384 B: [G 16][e^(G&7) 64] x 16B
    float* Xs   = (float*)(smem + 151552);     //   8192 B: [64 e][32 i] f32
    float* pbuf = (float*)(smem + 135168);     // alias Hs: [4][64 e][16 o] f32 partials

    const int tid = threadIdx.x;
    const int w   = tid >> 6;           // wave 0..7
    const int l31 = tid & 31;
    const int lh  = (tid >> 5) & 1;     // k-half within wave
    const int o15 = l31 & 15;
    const int ib  = l31 >> 4;           // i-lsb within packed col
    const int bid = blockIdx.x;
    const int ntl = (bid < NTL_BIG) ? 13 : 12;
    const int itn = 2 * ntl;

    // ---------------- prologue: stage W2 half 0, W1Ts; prefetch tile=bid ----------------
    float4 xreg; short8 efreg;
    float  b2v0, b2v1;
    {
        #pragma unroll
        for (int j = 0; j < 16; ++j)
            gll16(W2p + w * 8192 + j * 512 + (tid & 63) * 8, W2s + w * 8192 + j * 512);
    }
    {   // W1 [16][128] f32 -> W1Ts[c][k] bf16 swizzled (once per block)
        int g = tid * 4; int i = g >> 7; int c0 = g & 127;
        float4 v = *(const float4*)(W1 + g);
        float vv[4] = {v.x, v.y, v.z, v.w};
        #pragma unroll
        for (int u = 0; u < 4; ++u) {
            int c = c0 + u;
            W1Ts[c * 16 + (((i >> 3) ^ ((c >> 2) & 1)) << 3) + (i & 7)] = f2bf(vv[u]);
        }
    }
    {   // prefetch first tile: x gather (redundant esrc read per 8 threads) + ef frag
        int s = esrc[bid * 64 + (tid >> 3)];
        xreg = *(const float4*)(nf + (size_t)s * 32 + (tid & 7) * 4);
        int eL = l31 + ((w & 1) << 5);
        const float* ep = ef + (size_t)(bid * 64 + eL) * 16 + lh * 8;
        float4 a0 = *(const float4*)(ep);
        float4 a1 = *(const float4*)(ep + 4);
        efreg[0] = f2bf(a0.x); efreg[1] = f2bf(a0.y); efreg[2] = f2bf(a0.z); efreg[3] = f2bf(a0.w);
        efreg[4] = f2bf(a1.x); efreg[5] = f2bf(a1.y); efreg[6] = f2bf(a1.z); efreg[7] = f2bf(a1.w);
    }
    // per-pass b2 constants (pass 0): cols i=4w+ib and i=4w+2+ib at o = o15
    b2v0 = b2[(4 * w + ib) * 32 + o15];
    b2v1 = b2[(4 * w + 2 + ib) * 32 + o15];
    const int   cW1  = ((w >> 1) << 5) + l31;          // phase-1 hidden col
    const float b1v  = b1[cW1];

    __syncthreads();                                    // staging + gll drained
    const short8 w1frag = *(const short8*)(W1Ts + cW1 * 16 + ((lh ^ ((cW1 >> 2) & 1)) << 3));

    for (int it = 0; it < itn; ++it) {
        const int pass = (it >= ntl) ? 1 : 0;
        const int tile = bid + (it - pass * ntl) * NBLK;
        const int ebase = tile * 64;

        if (it == ntl) {   // restage W2 half 1 (prev W2s reads ended before last A-barrier)
            #pragma unroll
            for (int j = 0; j < 16; ++j)
                gll16(W2p + 65536 + w * 8192 + j * 512 + (tid & 63) * 8, W2s + w * 8192 + j * 512);
            b2v0 = b2[(4 * w + ib) * 32 + 16 + o15];
            b2v1 = b2[(4 * w + 2 + ib) * 32 + 16 + o15];
        }
        __syncthreads();   // D: staging done (vmcnt) AND prev iter's pbuf reads done

        // ---- phase 0: commit prefetched x ----
        *(float4*)(Xs + (tid >> 3) * 32 + (tid & 7) * 4) = xreg;

        // ---- phase 1: h = relu(ef@W1+b1) -> Hs ----
        {
            f32x16 hacc;
            #pragma unroll
            for (int q = 0; q < 16; ++q) hacc[q] = 0.f;
            hacc = __builtin_amdgcn_mfma_f32_32x32x16_bf16(efreg, w1frag, hacc, 0, 0, 0);
            const int mh = w & 1, G1 = cW1 >> 3, j1 = cW1 & 7;
            #pragma unroll
            for (int r = 0; r < 16; ++r) {
                int ee = (r & 3) + ((r >> 2) << 3) + (lh << 2) + (mh << 5);
                float v = fmaxf(hacc[r] + b1v, 0.f);
                Hs[G1 * 512 + ((ee ^ (G1 & 7)) << 3) + j1] = f2bf(v);
            }
        }
        __syncthreads();   // E: Hs, Xs visible

        // next-tile index for prefetch (clamped on last iteration)
        int nit = it + 1; if (nit >= itn) nit = it;
        const int npass = (nit >= ntl) ? 1 : 0;
        const int nebase = (bid + (nit - npass * ntl) * NBLK) * 64;

        // ---- phase 2: barrier-free K-loop, We half-tile in acc ----
        f32x16 acc00, acc01, acc10, acc11;   // [t][mh]
        #pragma unroll
        for (int q = 0; q < 16; ++q) { acc00[q] = 0.f; acc01[q] = 0.f; acc10[q] = 0.f; acc11[q] = 0.f; }
        int pre_s = 0;
        #pragma unroll
        for (int ks = 0; ks < 8; ++ks) {
            const int G  = 2 * ks + lh;
            const int ax = ((l31 ^ (G & 7)) << 3);
            short8 afr0 = *(const short8*)(Hs + G * 512 + ax);          // e = l31
            short8 afr1 = *(const short8*)(Hs + G * 512 + ax + 256);    // e = l31+32
            short8 bfr0 = *(const short8*)(W2s + ks * 8192 + (2 * w    ) * 512 + lh * 256 + l31 * 8);
            short8 bfr1 = *(const short8*)(W2s + ks * 8192 + (2 * w + 1) * 512 + lh * 256 + l31 * 8);
            acc00 = __builtin_amdgcn_mfma_f32_32x32x16_bf16(afr0, bfr0, acc00, 0, 0, 0);
            acc01 = __builtin_amdgcn_mfma_f32_32x32x16_bf16(afr1, bfr0, acc01, 0, 0, 0);
            acc10 = __builtin_amdgcn_mfma_f32_32x32x16_bf16(afr0, bfr1, acc10, 0, 0, 0);
            acc11 = __builtin_amdgcn_mfma_f32_32x32x16_bf16(afr1, bfr1, acc11, 0, 0, 0);
            if (ks == 1) pre_s = esrc[nebase + (tid >> 3)];
            if (ks == 3) {
                int eL = l31 + ((w & 1) << 5);
                const float* ep = ef + (size_t)(nebase + eL) * 16 + lh * 8;
                float4 a0 = *(const float4*)(ep);
                float4 a1 = *(const float4*)(ep + 4);
                efreg[0] = f2bf(a0.x); efreg[1] = f2bf(a0.y); efreg[2] = f2bf(a0.z); efreg[3] = f2bf(a0.w);
                efreg[4] = f2bf(a1.x); efreg[5] = f2bf(a1.y); efreg[6] = f2bf(a1.z); efreg[7] = f2bf(a1.w);
            }
            if (ks == 5) xreg = *(const float4*)(nf + (size_t)pre_s * 32 + (tid & 7) * 4);
        }

        // ---- phase 3: contract with x; pair-reduce i-lsb via shfl_xor(16) ----
        float sv0[16], sv1[16];
        #pragma unroll
        for (int r = 0; r < 16; ++r) {
            int e0 = (r & 3) + ((r >> 2) << 3) + (lh << 2);
            float4 xv = *(const float4*)(Xs + e0 * 32 + 4 * w);          // broadcast read
            float xa = ib ? xv.y : xv.x;                                 // i = 4w+ib
            float xb = ib ? xv.w : xv.z;                                 // i = 4w+2+ib
            float v = xa * (acc00[r] + b2v0) + xb * (acc10[r] + b2v1);
            v += __shfl_xor(v, 16);
            sv0[r] = v;
            float4 xw = *(const float4*)(Xs + (e0 + 32) * 32 + 4 * w);
            float xc = ib ? xw.y : xw.x;
            float xd = ib ? xw.w : xw.z;
            float v1 = xc * (acc01[r] + b2v0) + xd * (acc11[r] + b2v1);
            v1 += __shfl_xor(v1, 16);
            sv1[r] = v1;
        }

        __syncthreads();   // A: all K-loop Hs reads done -> pbuf (alias Hs) writable
        if (w < 4) {       // full-wave write: ib=0 lanes carry mh=0 rows, ib=1 carry mh=1
            #pragma unroll
            for (int r = 0; r < 16; ++r) {
                int e = (r & 3) + ((r >> 2) << 3) + (lh << 2) + (ib << 5);
                pbuf[(w << 10) + (e << 4) + o15] = ib ? sv1[r] : sv0[r];
            }
        }
        __syncthreads();   // B
        if (w >= 4) {
            #pragma unroll
            for (int r = 0; r < 16; ++r) {
                int e = (r & 3) + ((r >> 2) << 3) + (lh << 2) + (ib << 5);
                pbuf[((w - 4) << 10) + (e << 4) + o15] += ib ? sv1[r] : sv0[r];
            }
        }
        __syncthreads();   // C
        #pragma unroll
        for (int p2 = 0; p2 < 2; ++p2) {
            int idx = tid + (p2 << 9);           // 0..1023 = e*16 + o
            float v = pbuf[idx] + pbuf[idx + 1024] + pbuf[idx + 2048] + pbuf[idx + 3072];
            int e = idx >> 4, oo = idx & 15;
            int d = edst[ebase + e];
            atomicAdd(out + (size_t)d * 32 + (pass << 4) + oo, v);
        }
    }
}

extern "C" void kernel_launch(void* const* d_in, const int* in_sizes, int n_in,
                              void* d_out, int out_size, void* d_ws, size_t ws_size,
                              hipStream_t stream) {
    const float* nf   = (const float*)d_in[0];
    const float* ef   = (const float*)d_in[1];
    const int*   src  = (const int*)  d_in[2];
    const int*   dst  = (const int*)  d_in[3];
    const float* W1   = (const float*)d_in[4];
    const float* b1   = (const float*)d_in[5];
    const float* W2   = (const float*)d_in[6];
    const float* b2   = (const float*)d_in[7];
    const float* bias = (const float*)d_in[8];
    float* out = (float*)d_out;
    short* W2p = (short*)d_ws;                 // 262144 B bf16 W2, packed per o-half, LDS image

    // one-time opt-in for >64KB dynamic LDS (not a stream op; safe under graph capture)
    static bool init_done = false;
    if (!init_done) {
        hipFuncSetAttribute((const void*)mpnn_kernel,
                            hipFuncAttributeMaxDynamicSharedMemorySize, LDS_BYTES);
        init_done = true;
    }

    setup_kernel<<<OUT_BLKS + W2K_BLKS, 256, 0, stream>>>(W2, bias, out, W2p);
    mpnn_kernel<<<NBLK, 512, LDS_BYTES, stream>>>(nf, ef, src, dst, W1, b1, b2, W2p, out);
}

// Round 5
// 184.507 us; speedup vs baseline: 1.0366x; 1.0366x over previous
//
#include <hip/hip_runtime.h>

// NNConv / MPNN layer, fully fused — v3: pipelined atomics + pbuf de-conflict + fast setup.
//   h  = relu(ef @ W1 + b1)            [E,128]   (bf16 MFMA, K=16)
//   We = h @ W2 + b2                   [E,32,32] (bf16 MFMA, K=128, acc in VGPR/AGPR, never stored)
//   msg= einsum('ei,eio->eo', nf[src], We)       (fp32 VALU on acc tiles)
//   out= segment_sum(msg, dst) + bias            (fp32 global atomics, out pre-init to bias)
//
// Structure: 256 blocks (1/CU) x 512 thr (8 waves). o split in 2 halves; 128 KB bf16 W2
// per half staged ONCE into LDS (global_load_lds, source pre-packed by setup) and
// persistent while the block grid-strides its 12-13 edge tiles. K-loop barrier-free.
// v3 changes (from round-2 counters: MfmaUtil 18%, VALU 28%, HBM 5.5% -> latency-bound):
//  - atomics DEFERRED: values+addresses computed after barrier C into regs, issued in the
//    NEXT iteration's K-loop (ks==2, after pre_s load so counted vmcnt waits skip them),
//    drained at barrier A under ~1K cyc of MFMA instead of serially at barrier D.
//  - pbuf XOR (stored-row lsb ^= lh^ib = bit2^bit5 of e): 4-way bank conflict -> free.
//  - phase-3 x reads: direct broadcast ds_read_b32 (drops 64 cndmask selects/thread).
//  - setup: dest-major W2 pack (8 gathered loads + one 16B store/thread, was 64
//    scattered 2B stores/wave) + float4 out-init.

#define E_TOTAL   200000
#define N_NODES   50000
#define TILES     3125          // E_TOTAL / 64
#define OUT4      400000        // N_NODES*32 / 4
#define OUT4_BLKS 1563          // ceil(OUT4/256)
#define W2C_BLKS  64            // 16384 16B-chunks / 256
#define NBLK      256
#define NTL_BIG   53            // TILES % NBLK: blocks 0..52 own 13 tiles, rest 12
#define LDS_BYTES 159744        // 128K W2s + 4K W1Ts + 16K Hs + 8K Xs

typedef short short8  __attribute__((ext_vector_type(8)));
typedef float f32x16  __attribute__((ext_vector_type(16)));

__device__ __forceinline__ short f2bf(float f) {
    // round-to-nearest-even fp32 -> bf16 (inputs finite)
    union { float f; unsigned u; } cv; cv.f = f;
    unsigned r = cv.u + 0x7fffu + ((cv.u >> 16) & 1u);
    return (short)(r >> 16);
}

__device__ __forceinline__ void gll16(const short* gsrc, short* ldst) {
    // async global->LDS, 16B/lane; LDS dest = wave-uniform base + lane*16
    __builtin_amdgcn_global_load_lds(
        (const __attribute__((address_space(1))) unsigned int*)gsrc,
        (__attribute__((address_space(3))) unsigned int*)ldst, 16, 0, 0);
}

// ---------------- setup: out = bias (float4); W2 f32 -> bf16 packed LDS image (dest-major) ----
// W2p short idx = p*65536 + ks*8192 + ct*512 + lhg*256 + cc*8 + j
//   where c = ct*32+cc (= i*16 + o15), k = ks*16 + lhg*8 + j, src = W2[k*1024 + i*32 + p*16 + o15]
__global__ __launch_bounds__(256) void setup_kernel(const float* __restrict__ W2,
                                                    const float* __restrict__ bias,
                                                    float* __restrict__ out,
                                                    short* __restrict__ W2p) {
    int bid = blockIdx.x, tid = threadIdx.x;
    if (bid < OUT4_BLKS) {
        int i4 = bid * 256 + tid;
        if (i4 < OUT4) {
            float4 bv = *(const float4*)(bias + ((i4 & 7) << 2));
            *(float4*)(out + (size_t)i4 * 4) = bv;
        }
    } else {
        int q = (bid - OUT4_BLKS) * 256 + tid;    // 0..16383: one 16B dest chunk
        int p  = q >> 13;
        int ch = q & 8191;
        int ks = ch >> 10, ct = (ch >> 6) & 15, lhg = (ch >> 5) & 1, cc = ch & 31;
        int c  = ct * 32 + cc;
        int i  = c >> 4, o15 = c & 15;
        int ci = i * 32 + p * 16 + o15;
        int kb = ks * 16 + lhg * 8;
        short8 pk;
        #pragma unroll
        for (int j = 0; j < 8; ++j) pk[j] = f2bf(W2[(size_t)(kb + j) * 1024 + ci]);
        *(short8*)(W2p + (size_t)q * 8) = pk;
    }
}

// ---------------- main fused kernel ----------------
__global__ __launch_bounds__(512, 2) void mpnn_kernel(const float* __restrict__ nf,
                                                      const float* __restrict__ ef,
                                                      const int*   __restrict__ esrc,
                                                      const int*   __restrict__ edst,
                                                      const float* __restrict__ W1,
                                                      const float* __restrict__ b1,
                                                      const float* __restrict__ b2,
                                                      const short* __restrict__ W2p,
                                                      float* __restrict__ out) {
    extern __shared__ __align__(16) unsigned char smem[];
    short* W2s  = (short*)(smem);              // 131072 B: one o-half of W2, persistent per pass
    short* W1Ts = (short*)(smem + 131072);     //   4096 B: [128 c][16 k] bf16 swizzled, persistent
    short* Hs   = (short*)(smem + 135168);     //  16384 B: [G 16][e^(G&7) 64] x 16B
    float* Xs   = (float*)(smem + 151552);     //   8192 B: [64 e][32 i] f32
    float* pbuf = (float*)(smem + 135168);     // alias Hs: [4][64 e'][16 o] f32, e' = e^(b2^b5 of e)

    const int tid = threadIdx.x;
    const int w   = tid >> 6;           // wave 0..7
    const int l31 = tid & 31;
    const int lh  = (tid >> 5) & 1;     // k-half within wave
    const int o15 = l31 & 15;
    const int ib  = l31 >> 4;           // i-lsb within packed col
    const int xbw = lh ^ ib;            // pbuf row-lsb XOR (= bit2^bit5 of this lane's e rows)
    const int bid = blockIdx.x;
    const int ntl = (bid < NTL_BIG) ? 13 : 12;
    const int itn = 2 * ntl;

    // ---------------- prologue: stage W2 half 0, W1Ts; prefetch tile=bid ----------------
    float4 xreg; short8 efreg;
    float  b2v0, b2v1;
    {
        #pragma unroll
        for (int j = 0; j < 16; ++j)
            gll16(W2p + w * 8192 + j * 512 + (tid & 63) * 8, W2s + w * 8192 + j * 512);
    }
    {   // W1 [16][128] f32 -> W1Ts[c][k] bf16 swizzled (once per block)
        int g = tid * 4; int i = g >> 7; int c0 = g & 127;
        float4 v = *(const float4*)(W1 + g);
        float vv[4] = {v.x, v.y, v.z, v.w};
        #pragma unroll
        for (int u = 0; u < 4; ++u) {
            int c = c0 + u;
            W1Ts[c * 16 + (((i >> 3) ^ ((c >> 2) & 1)) << 3) + (i & 7)] = f2bf(vv[u]);
        }
    }
    {   // prefetch first tile: x gather (redundant esrc read per 8 threads) + ef frag
        int s = esrc[bid * 64 + (tid >> 3)];
        xreg = *(const float4*)(nf + (size_t)s * 32 + (tid & 7) * 4);
        int eL = l31 + ((w & 1) << 5);
        const float* ep = ef + (size_t)(bid * 64 + eL) * 16 + lh * 8;
        float4 a0 = *(const float4*)(ep);
        float4 a1 = *(const float4*)(ep + 4);
        efreg[0] = f2bf(a0.x); efreg[1] = f2bf(a0.y); efreg[2] = f2bf(a0.z); efreg[3] = f2bf(a0.w);
        efreg[4] = f2bf(a1.x); efreg[5] = f2bf(a1.y); efreg[6] = f2bf(a1.z); efreg[7] = f2bf(a1.w);
    }
    // per-pass b2 constants (pass 0): cols i=4w+ib and i=4w+2+ib at o = o15
    b2v0 = b2[(4 * w + ib) * 32 + o15];
    b2v1 = b2[(4 * w + 2 + ib) * 32 + o15];
    const int   cW1  = ((w >> 1) << 5) + l31;          // phase-1 hidden col
    const float b1v  = b1[cW1];

    __syncthreads();                                    // staging + gll drained
    const short8 w1frag = *(const short8*)(W1Ts + cW1 * 16 + ((lh ^ ((cW1 >> 2) & 1)) << 3));

    // deferred-atomic pending state (issued one iteration later, flushed after loop)
    float  pv0 = 0.f, pv1 = 0.f;
    float *pa0 = out, *pa1 = out;

    for (int it = 0; it < itn; ++it) {
        const int pass = (it >= ntl) ? 1 : 0;
        const int tile = bid + (it - pass * ntl) * NBLK;
        const int ebase = tile * 64;

        if (it == ntl) {   // restage W2 half 1 (prev W2s reads ended before last A-barrier)
            #pragma unroll
            for (int j = 0; j < 16; ++j)
                gll16(W2p + 65536 + w * 8192 + j * 512 + (tid & 63) * 8, W2s + w * 8192 + j * 512);
            b2v0 = b2[(4 * w + ib) * 32 + 16 + o15];
            b2v1 = b2[(4 * w + 2 + ib) * 32 + 16 + o15];
        }
        __syncthreads();   // D: staging done (vmcnt) AND prev iter's pbuf reads done

        // ---- phase 0: commit prefetched x ----
        *(float4*)(Xs + (tid >> 3) * 32 + (tid & 7) * 4) = xreg;

        // ---- phase 1: h = relu(ef@W1+b1) -> Hs ----
        {
            f32x16 hacc;
            #pragma unroll
            for (int q = 0; q < 16; ++q) hacc[q] = 0.f;
            hacc = __builtin_amdgcn_mfma_f32_32x32x16_bf16(efreg, w1frag, hacc, 0, 0, 0);
            const int mh = w & 1, G1 = cW1 >> 3, j1 = cW1 & 7;
            #pragma unroll
            for (int r = 0; r < 16; ++r) {
                int ee = (r & 3) + ((r >> 2) << 3) + (lh << 2) + (mh << 5);
                float v = fmaxf(hacc[r] + b1v, 0.f);
                Hs[G1 * 512 + ((ee ^ (G1 & 7)) << 3) + j1] = f2bf(v);
            }
        }
        __syncthreads();   // E: Hs, Xs visible

        // next-tile index for prefetch (clamped on last iteration)
        int nit = it + 1; if (nit >= itn) nit = it;
        const int npass = (nit >= ntl) ? 1 : 0;
        const int nebase = (bid + (nit - npass * ntl) * NBLK) * 64;

        // ---- phase 2: barrier-free K-loop; prev tile's atomics issued at ks==2 ----
        f32x16 acc00, acc01, acc10, acc11;   // [t][mh]
        #pragma unroll
        for (int q = 0; q < 16; ++q) { acc00[q] = 0.f; acc01[q] = 0.f; acc10[q] = 0.f; acc11[q] = 0.f; }
        int pre_s = 0;
        #pragma unroll
        for (int ks = 0; ks < 8; ++ks) {
            const int G  = 2 * ks + lh;
            const int ax = ((l31 ^ (G & 7)) << 3);
            short8 afr0 = *(const short8*)(Hs + G * 512 + ax);          // e = l31
            short8 afr1 = *(const short8*)(Hs + G * 512 + ax + 256);    // e = l31+32
            short8 bfr0 = *(const short8*)(W2s + ks * 8192 + (2 * w    ) * 512 + lh * 256 + l31 * 8);
            short8 bfr1 = *(const short8*)(W2s + ks * 8192 + (2 * w + 1) * 512 + lh * 256 + l31 * 8);
            acc00 = __builtin_amdgcn_mfma_f32_32x32x16_bf16(afr0, bfr0, acc00, 0, 0, 0);
            acc01 = __builtin_amdgcn_mfma_f32_32x32x16_bf16(afr1, bfr0, acc01, 0, 0, 0);
            acc10 = __builtin_amdgcn_mfma_f32_32x32x16_bf16(afr0, bfr1, acc10, 0, 0, 0);
            acc11 = __builtin_amdgcn_mfma_f32_32x32x16_bf16(afr1, bfr1, acc11, 0, 0, 0);
            if (ks == 1) pre_s = esrc[nebase + (tid >> 3)];
            if (ks == 2 && it > 0) {            // prev tile's atomics: ~6 ks-steps to drain
                atomicAdd(pa0, pv0);
                atomicAdd(pa1, pv1);
            }
            if (ks == 3) {
                int eL = l31 + ((w & 1) << 5);
                const float* ep = ef + (size_t)(nebase + eL) * 16 + lh * 8;
                float4 a0 = *(const float4*)(ep);
                float4 a1 = *(const float4*)(ep + 4);
                efreg[0] = f2bf(a0.x); efreg[1] = f2bf(a0.y); efreg[2] = f2bf(a0.z); efreg[3] = f2bf(a0.w);
                efreg[4] = f2bf(a1.x); efreg[5] = f2bf(a1.y); efreg[6] = f2bf(a1.z); efreg[7] = f2bf(a1.w);
            }
            if (ks == 5) xreg = *(const float4*)(nf + (size_t)pre_s * 32 + (tid & 7) * 4);
        }

        // ---- phase 3: contract with x (broadcast ds_read_b32); pair-reduce via shfl_xor(16) ----
        const int xc0 = 4 * w + ib, xc1 = 4 * w + 2 + ib;
        float sv0[16], sv1[16];
        #pragma unroll
        for (int r = 0; r < 16; ++r) {
            int e0 = (r & 3) + ((r >> 2) << 3) + (lh << 2);
            float xa = Xs[e0 * 32 + xc0];
            float xb = Xs[e0 * 32 + xc1];
            float v = xa * (acc00[r] + b2v0) + xb * (acc10[r] + b2v1);
            v += __shfl_xor(v, 16);
            sv0[r] = v;
            float xc = Xs[(e0 + 32) * 32 + xc0];
            float xd = Xs[(e0 + 32) * 32 + xc1];
            float v1 = xc * (acc01[r] + b2v0) + xd * (acc11[r] + b2v1);
            v1 += __shfl_xor(v1, 16);
            sv1[r] = v1;
        }

        __syncthreads();   // A: all K-loop Hs reads done -> pbuf (alias Hs) writable; atomics drained
        if (w < 4) {       // full-wave write; stored row = e ^ (lh^ib) spreads bank halves
            #pragma unroll
            for (int r = 0; r < 16; ++r) {
                int e = (r & 3) + ((r >> 2) << 3) + (lh << 2) + (ib << 5);
                pbuf[(w << 10) + ((e ^ xbw) << 4) + o15] = ib ? sv1[r] : sv0[r];
            }
        }
        __syncthreads();   // B
        if (w >= 4) {
            #pragma unroll
            for (int r = 0; r < 16; ++r) {
                int e = (r & 3) + ((r >> 2) << 3) + (lh << 2) + (ib << 5);
                pbuf[((w - 4) << 10) + ((e ^ xbw) << 4) + o15] += ib ? sv1[r] : sv0[r];
            }
        }
        __syncthreads();   // C
        {   // final reduce -> pending registers (atomics issued next iteration / flushed)
            int idx = tid;
            int e = idx >> 4, oo = idx & 15;
            int xbE = ((e >> 2) ^ (e >> 5)) & 1;
            int a = ((e ^ xbE) << 4) + oo;
            pv0 = pbuf[a] + pbuf[a + 1024] + pbuf[a + 2048] + pbuf[a + 3072];
            pa0 = out + (size_t)edst[ebase + e] * 32 + (pass << 4) + oo;
            idx = tid + 512;
            e = idx >> 4; oo = idx & 15;
            xbE = ((e >> 2) ^ (e >> 5)) & 1;
            a = ((e ^ xbE) << 4) + oo;
            pv1 = pbuf[a] + pbuf[a + 1024] + pbuf[a + 2048] + pbuf[a + 3072];
            pa1 = out + (size_t)edst[ebase + e] * 32 + (pass << 4) + oo;
        }
    }
    // flush last tile's atomics
    atomicAdd(pa0, pv0);
    atomicAdd(pa1, pv1);
}

extern "C" void kernel_launch(void* const* d_in, const int* in_sizes, int n_in,
                              void* d_out, int out_size, void* d_ws, size_t ws_size,
                              hipStream_t stream) {
    const float* nf   = (const float*)d_in[0];
    const float* ef   = (const float*)d_in[1];
    const int*   src  = (const int*)  d_in[2];
    const int*   dst  = (const int*)  d_in[3];
    const float* W1   = (const float*)d_in[4];
    const float* b1   = (const float*)d_in[5];
    const float* W2   = (const float*)d_in[6];
    const float* b2   = (const float*)d_in[7];
    const float* bias = (const float*)d_in[8];
    float* out = (float*)d_out;
    short* W2p = (short*)d_ws;                 // 262144 B bf16 W2, packed per o-half, LDS image

    // one-time opt-in for >64KB dynamic LDS (not a stream op; safe under graph capture)
    static bool init_done = false;
    if (!init_done) {
        hipFuncSetAttribute((const void*)mpnn_kernel,
                            hipFuncAttributeMaxDynamicSharedMemorySize, LDS_BYTES);
        init_done = true;
    }

    setup_kernel<<<OUT4_BLKS + W2C_BLKS, 256, 0, stream>>>(W2, bias, out, W2p);
    mpnn_kernel<<<NBLK, 512, LDS_BYTES, stream>>>(nf, ef, src, dst, W1, b1, b2, W2p, out);
}

// Round 8
// 165.648 us; speedup vs baseline: 1.1546x; 1.1139x over previous
//
#include <hip/hip_runtime.h>

// NNConv / MPNN layer, fully fused — v4: epilogue LDS-instruction diet.
//   h  = relu(ef @ W1 + b1)            [E,128]   (bf16 MFMA, K=16)
//   We = h @ W2 + b2                   [E,32,32] (bf16 MFMA, K=128, acc in regs, never stored)
//   msg= einsum('ei,eio->eo', nf[src], We)       (fp32 VALU on acc tiles)
//   out= segment_sum(msg, dst) + bias            (fp32 global atomics, out pre-init to bias)
//
// Structure: 256 blocks (1/CU) x 512 thr (8 waves), o split in 2 halves, 128 KB bf16 W2
// per half persistent in LDS (global_load_lds, pre-packed by setup). K-loop barrier-free.
// v4 (from round-5 counters: MfmaUtil 18.8, VALU 27, HBM 5.7, conflicts fixed -> the
// bottleneck is LDS *instruction issue*, dominated by the epilogue: 64 b32 Xs reads +
// ~40 pbuf ops per wave per pass vs only 32 K-loop b128):
//  - Xs transposed -> XsT[i 32][e pad 68] f32: phase-3 x-loads become 16 broadcast
//    ds_read_b128 per wave (4 per r-quad), was 64 ds_read_b32. Phase-0 commit = 4
//    scalar stores (4-way banked, 4 ops/pass — negligible).
//  - pbuf -> 8 single-stage slabs (32 KB, aliasing dead W1Ts+Hs+XsT after barrier A):
//    every wave writes its own slab, final reduce sums 8; kills the RMW stage and
//    barrier B (5 -> 4 barriers/pass). DS-ops/wave/pass 186 -> ~133.
//  - unchanged: deferred atomics (issued at ks==2 of next iter), K-loop, phase-1, setup.

#define E_TOTAL   200000
#define N_NODES   50000
#define TILES     3125          // E_TOTAL / 64
#define OUT4      400000        // N_NODES*32 / 4
#define OUT4_BLKS 1563          // ceil(OUT4/256)
#define W2C_BLKS  64            // 16384 16B-chunks / 256
#define NBLK      256
#define NTL_BIG   53            // TILES % NBLK: blocks 0..52 own 13 tiles, rest 12
#define LDS_BYTES 163840        // 128K W2s + 32K pbuf-alias region (= 160 KiB exactly)

typedef short short8  __attribute__((ext_vector_type(8)));
typedef float f32x4   __attribute__((ext_vector_type(4)));
typedef float f32x16  __attribute__((ext_vector_type(16)));

__device__ __forceinline__ short f2bf(float f) {
    // round-to-nearest-even fp32 -> bf16 (inputs finite)
    union { float f; unsigned u; } cv; cv.f = f;
    unsigned r = cv.u + 0x7fffu + ((cv.u >> 16) & 1u);
    return (short)(r >> 16);
}

__device__ __forceinline__ void gll16(const short* gsrc, short* ldst) {
    // async global->LDS, 16B/lane; LDS dest = wave-uniform base + lane*16
    __builtin_amdgcn_global_load_lds(
        (const __attribute__((address_space(1))) unsigned int*)gsrc,
        (__attribute__((address_space(3))) unsigned int*)ldst, 16, 0, 0);
}

// ---------------- setup: out = bias (float4); W2 f32 -> bf16 packed LDS image (dest-major) ----
// W2p short idx = p*65536 + ks*8192 + ct*512 + lhg*256 + cc*8 + j
//   where c = ct*32+cc (= i*16 + o15), k = ks*16 + lhg*8 + j, src = W2[k*1024 + i*32 + p*16 + o15]
__global__ __launch_bounds__(256) void setup_kernel(const float* __restrict__ W2,
                                                    const float* __restrict__ bias,
                                                    float* __restrict__ out,
                                                    short* __restrict__ W2p) {
    int bid = blockIdx.x, tid = threadIdx.x;
    if (bid < OUT4_BLKS) {
        int i4 = bid * 256 + tid;
        if (i4 < OUT4) {
            float4 bv = *(const float4*)(bias + ((i4 & 7) << 2));
            *(float4*)(out + (size_t)i4 * 4) = bv;
        }
    } else {
        int q = (bid - OUT4_BLKS) * 256 + tid;    // 0..16383: one 16B dest chunk
        int p  = q >> 13;
        int ch = q & 8191;
        int ks = ch >> 10, ct = (ch >> 6) & 15, lhg = (ch >> 5) & 1, cc = ch & 31;
        int c  = ct * 32 + cc;
        int i  = c >> 4, o15 = c & 15;
        int ci = i * 32 + p * 16 + o15;
        int kb = ks * 16 + lhg * 8;
        short8 pk;
        #pragma unroll
        for (int j = 0; j < 8; ++j) pk[j] = f2bf(W2[(size_t)(kb + j) * 1024 + ci]);
        *(short8*)(W2p + (size_t)q * 8) = pk;
    }
}

// ---------------- main fused kernel ----------------
__global__ __launch_bounds__(512, 2) void mpnn_kernel(const float* __restrict__ nf,
                                                      const float* __restrict__ ef,
                                                      const int*   __restrict__ esrc,
                                                      const int*   __restrict__ edst,
                                                      const float* __restrict__ W1,
                                                      const float* __restrict__ b1,
                                                      const float* __restrict__ b2,
                                                      const short* __restrict__ W2p,
                                                      float* __restrict__ out) {
    extern __shared__ __align__(16) unsigned char smem[];
    short* W2s  = (short*)(smem);              // 131072 B: one o-half of W2, persistent per pass
    short* W1Ts = (short*)(smem + 131072);     //   4096 B: [128 c][16 k] bf16 swizzled (dead after prologue)
    short* Hs   = (short*)(smem + 135168);     //  16384 B: [G 16][e^(G&7) 64] x 16B     (live D->A)
    float* XsT  = (float*)(smem + 151552);     //   8704 B: [32 i][68 e-pad] f32         (live phase0->A)
    float* pbuf = (float*)(smem + 131072);     //  32768 B: 8 slabs [64 e'][16 o] f32    (live A->next D)

    const int tid = threadIdx.x;
    const int w   = tid >> 6;           // wave 0..7
    const int l31 = tid & 31;
    const int lh  = (tid >> 5) & 1;     // k-half within wave
    const int o15 = l31 & 15;
    const int ib  = l31 >> 4;           // i-lsb within packed col
    const int xbw = lh ^ ib;            // pbuf row-lsb XOR (= bit2^bit5 of this lane's e rows)
    const int bid = blockIdx.x;
    const int ntl = (bid < NTL_BIG) ? 13 : 12;
    const int itn = 2 * ntl;

    // ---------------- prologue: stage W2 half 0, W1Ts; prefetch tile=bid ----------------
    float4 xreg; short8 efreg;
    float  b2v0, b2v1;
    {
        #pragma unroll
        for (int j = 0; j < 16; ++j)
            gll16(W2p + w * 8192 + j * 512 + (tid & 63) * 8, W2s + w * 8192 + j * 512);
    }
    {   // W1 [16][128] f32 -> W1Ts[c][k] bf16 swizzled (once per block)
        int g = tid * 4; int i = g >> 7; int c0 = g & 127;
        float4 v = *(const float4*)(W1 + g);
        float vv[4] = {v.x, v.y, v.z, v.w};
        #pragma unroll
        for (int u = 0; u < 4; ++u) {
            int c = c0 + u;
            W1Ts[c * 16 + (((i >> 3) ^ ((c >> 2) & 1)) << 3) + (i & 7)] = f2bf(vv[u]);
        }
    }
    {   // prefetch first tile: x gather (redundant esrc read per 8 threads) + ef frag
        int s = esrc[bid * 64 + (tid >> 3)];
        xreg = *(const float4*)(nf + (size_t)s * 32 + (tid & 7) * 4);
        int eL = l31 + ((w & 1) << 5);
        const float* ep = ef + (size_t)(bid * 64 + eL) * 16 + lh * 8;
        float4 a0 = *(const float4*)(ep);
        float4 a1 = *(const float4*)(ep + 4);
        efreg[0] = f2bf(a0.x); efreg[1] = f2bf(a0.y); efreg[2] = f2bf(a0.z); efreg[3] = f2bf(a0.w);
        efreg[4] = f2bf(a1.x); efreg[5] = f2bf(a1.y); efreg[6] = f2bf(a1.z); efreg[7] = f2bf(a1.w);
    }
    // per-pass b2 constants (pass 0): cols i=4w+ib and i=4w+2+ib at o = o15
    b2v0 = b2[(4 * w + ib) * 32 + o15];
    b2v1 = b2[(4 * w + 2 + ib) * 32 + o15];
    const int   cW1  = ((w >> 1) << 5) + l31;          // phase-1 hidden col
    const float b1v  = b1[cW1];

    __syncthreads();                                    // staging + gll drained
    const short8 w1frag = *(const short8*)(W1Ts + cW1 * 16 + ((lh ^ ((cW1 >> 2) & 1)) << 3));
    // W1Ts is dead from here on (w1frag in regs) -> its LDS is part of the pbuf alias.

    // deferred-atomic pending state (issued one iteration later, flushed after loop)
    float  pv0 = 0.f, pv1 = 0.f;
    float *pa0 = out, *pa1 = out;

    for (int it = 0; it < itn; ++it) {
        const int pass = (it >= ntl) ? 1 : 0;
        const int tile = bid + (it - pass * ntl) * NBLK;
        const int ebase = tile * 64;

        if (it == ntl) {   // restage W2 half 1 (prev W2s reads ended before last A-barrier)
            #pragma unroll
            for (int j = 0; j < 16; ++j)
                gll16(W2p + 65536 + w * 8192 + j * 512 + (tid & 63) * 8, W2s + w * 8192 + j * 512);
            b2v0 = b2[(4 * w + ib) * 32 + 16 + o15];
            b2v1 = b2[(4 * w + 2 + ib) * 32 + 16 + o15];
        }
        __syncthreads();   // D: staging done (vmcnt) AND prev iter's pbuf reads done

        // ---- phase 0: commit prefetched x -> XsT (transposed) ----
        {
            int e = tid >> 3, i4 = (tid & 7) * 4;
            XsT[(i4 + 0) * 68 + e] = xreg.x;
            XsT[(i4 + 1) * 68 + e] = xreg.y;
            XsT[(i4 + 2) * 68 + e] = xreg.z;
            XsT[(i4 + 3) * 68 + e] = xreg.w;
        }

        // ---- phase 1: h = relu(ef@W1+b1) -> Hs ----
        {
            f32x16 hacc;
            #pragma unroll
            for (int q = 0; q < 16; ++q) hacc[q] = 0.f;
            hacc = __builtin_amdgcn_mfma_f32_32x32x16_bf16(efreg, w1frag, hacc, 0, 0, 0);
            const int mh = w & 1, G1 = cW1 >> 3, j1 = cW1 & 7;
            #pragma unroll
            for (int r = 0; r < 16; ++r) {
                int ee = (r & 3) + ((r >> 2) << 3) + (lh << 2) + (mh << 5);
                float v = fmaxf(hacc[r] + b1v, 0.f);
                Hs[G1 * 512 + ((ee ^ (G1 & 7)) << 3) + j1] = f2bf(v);
            }
        }
        __syncthreads();   // E: Hs, XsT visible

        // next-tile index for prefetch (clamped on last iteration)
        int nit = it + 1; if (nit >= itn) nit = it;
        const int npass = (nit >= ntl) ? 1 : 0;
        const int nebase = (bid + (nit - npass * ntl) * NBLK) * 64;

        // ---- phase 2: barrier-free K-loop; prev tile's atomics issued at ks==2 ----
        f32x16 acc00, acc01, acc10, acc11;   // [t][mh]
        #pragma unroll
        for (int q = 0; q < 16; ++q) { acc00[q] = 0.f; acc01[q] = 0.f; acc10[q] = 0.f; acc11[q] = 0.f; }
        int pre_s = 0;
        #pragma unroll
        for (int ks = 0; ks < 8; ++ks) {
            const int G  = 2 * ks + lh;
            const int ax = ((l31 ^ (G & 7)) << 3);
            short8 afr0 = *(const short8*)(Hs + G * 512 + ax);          // e = l31
            short8 afr1 = *(const short8*)(Hs + G * 512 + ax + 256);    // e = l31+32
            short8 bfr0 = *(const short8*)(W2s + ks * 8192 + (2 * w    ) * 512 + lh * 256 + l31 * 8);
            short8 bfr1 = *(const short8*)(W2s + ks * 8192 + (2 * w + 1) * 512 + lh * 256 + l31 * 8);
            acc00 = __builtin_amdgcn_mfma_f32_32x32x16_bf16(afr0, bfr0, acc00, 0, 0, 0);
            acc01 = __builtin_amdgcn_mfma_f32_32x32x16_bf16(afr1, bfr0, acc01, 0, 0, 0);
            acc10 = __builtin_amdgcn_mfma_f32_32x32x16_bf16(afr0, bfr1, acc10, 0, 0, 0);
            acc11 = __builtin_amdgcn_mfma_f32_32x32x16_bf16(afr1, bfr1, acc11, 0, 0, 0);
            if (ks == 1) pre_s = esrc[nebase + (tid >> 3)];
            if (ks == 2 && it > 0) {            // prev tile's atomics: ~6 ks-steps to drain
                atomicAdd(pa0, pv0);
                atomicAdd(pa1, pv1);
            }
            if (ks == 3) {
                int eL = l31 + ((w & 1) << 5);
                const float* ep = ef + (size_t)(nebase + eL) * 16 + lh * 8;
                float4 a0 = *(const float4*)(ep);
                float4 a1 = *(const float4*)(ep + 4);
                efreg[0] = f2bf(a0.x); efreg[1] = f2bf(a0.y); efreg[2] = f2bf(a0.z); efreg[3] = f2bf(a0.w);
                efreg[4] = f2bf(a1.x); efreg[5] = f2bf(a1.y); efreg[6] = f2bf(a1.z); efreg[7] = f2bf(a1.w);
            }
            if (ks == 5) xreg = *(const float4*)(nf + (size_t)pre_s * 32 + (tid & 7) * 4);
        }

        // ---- phase 3: contract with x via 16 broadcast b128 XsT loads; pair-reduce shfl_xor(16) ----
        const int xc0 = 4 * w + ib, xc1 = 4 * w + 2 + ib;
        float sv0[16], sv1[16];
        #pragma unroll
        for (int rq = 0; rq < 4; ++rq) {
            const int eb = 8 * rq + 4 * lh;                 // e-base for r = rq*4+u (u = r&3)
            f32x4 A0 = *(const f32x4*)(XsT + xc0 * 68 + eb);        // x[eb..eb+3][xc0]
            f32x4 B0 = *(const f32x4*)(XsT + xc1 * 68 + eb);
            f32x4 A1 = *(const f32x4*)(XsT + xc0 * 68 + eb + 32);   // e-half 1
            f32x4 B1 = *(const f32x4*)(XsT + xc1 * 68 + eb + 32);
            #pragma unroll
            for (int u = 0; u < 4; ++u) {
                int r = rq * 4 + u;
                float v = A0[u] * (acc00[r] + b2v0) + B0[u] * (acc10[r] + b2v1);
                v += __shfl_xor(v, 16);
                sv0[r] = v;
                float v1 = A1[u] * (acc01[r] + b2v0) + B1[u] * (acc11[r] + b2v1);
                v1 += __shfl_xor(v1, 16);
                sv1[r] = v1;
            }
        }

        __syncthreads();   // A: K-loop Hs reads + phase-3 XsT reads done -> pbuf region writable
        #pragma unroll
        for (int r = 0; r < 16; ++r) {       // every wave -> its own slab, conflict-free via xbw
            int e = (r & 3) + ((r >> 2) << 3) + (lh << 2) + (ib << 5);
            pbuf[(w << 10) + ((e ^ xbw) << 4) + o15] = ib ? sv1[r] : sv0[r];
        }
        __syncthreads();   // C
        {   // final reduce over 8 slabs -> pending registers (atomics issued next iteration)
            int idx = tid;
            int e = idx >> 4, oo = idx & 15;
            int xbE = ((e >> 2) ^ (e >> 5)) & 1;
            int a = ((e ^ xbE) << 4) + oo;
            pv0 = ((pbuf[a]          + pbuf[a + 1024]) + (pbuf[a + 2048] + pbuf[a + 3072]))
                + ((pbuf[a + 4096]   + pbuf[a + 5120]) + (pbuf[a + 6144] + pbuf[a + 7168]));
            pa0 = out + (size_t)edst[ebase + e] * 32 + (pass << 4) + oo;
            idx = tid + 512;
            e = idx >> 4; oo = idx & 15;
            xbE = ((e >> 2) ^ (e >> 5)) & 1;
            a = ((e ^ xbE) << 4) + oo;
            pv1 = ((pbuf[a]          + pbuf[a + 1024]) + (pbuf[a + 2048] + pbuf[a + 3072]))
                + ((pbuf[a + 4096]   + pbuf[a + 5120]) + (pbuf[a + 6144] + pbuf[a + 7168]));
            pa1 = out + (size_t)edst[ebase + e] * 32 + (pass << 4) + oo;
        }
    }
    // flush last tile's atomics
    atomicAdd(pa0, pv0);
    atomicAdd(pa1, pv1);
}

extern "C" void kernel_launch(void* const* d_in, const int* in_sizes, int n_in,
                              void* d_out, int out_size, void* d_ws, size_t ws_size,
                              hipStream_t stream) {
    const float* nf   = (const float*)d_in[0];
    const float* ef   = (const float*)d_in[1];
    const int*   src  = (const int*)  d_in[2];
    const int*   dst  = (const int*)  d_in[3];
    const float* W1   = (const float*)d_in[4];
    const float* b1   = (const float*)d_in[5];
    const float* W2   = (const float*)d_in[6];
    const float* b2   = (const float*)d_in[7];
    const float* bias = (const float*)d_in[8];
    float* out = (float*)d_out;
    short* W2p = (short*)d_ws;                 // 262144 B bf16 W2, packed per o-half, LDS image

    // one-time opt-in for >64KB dynamic LDS (not a stream op; safe under graph capture)
    static bool init_done = false;
    if (!init_done) {
        hipFuncSetAttribute((const void*)mpnn_kernel,
                            hipFuncAttributeMaxDynamicSharedMemorySize, LDS_BYTES);
        init_done = true;
    }

    setup_kernel<<<OUT4_BLKS + W2C_BLKS, 256, 0, stream>>>(W2, bias, out, W2p);
    mpnn_kernel<<<NBLK, 512, LDS_BYTES, stream>>>(nf, ef, src, dst, W1, b1, b2, W2p, out);
}